// Round 1
// baseline (898.513 us; speedup 1.0000x reference)
//
#include <hip/hip_runtime.h>
#include <cfloat>
#include <cmath>

// NoisyTopKRouter eval-mode: logits = x @ W^T, top-2 + softmax over top-2.
// N=131072, D=2048, E=16. Outputs (concatenated flat in d_out as float32):
//   [0 .. 2N)   topk indices (written as float values, ref is int64)
//   [2N .. 4N)  gating weights (softmax over the two top logits)

constexpr int D = 2048;
constexpr int E = 16;
constexpr int R = 8;            // rows per 16-lane expert-group
constexpr int BLOCK = 256;      // 4 waves
constexpr int ROWS_PER_BLOCK = (BLOCK / 16) * R;  // 128

__global__ __launch_bounds__(BLOCK, 4) void router_kernel(
    const float* __restrict__ x, const float* __restrict__ W,
    float* __restrict__ out, int N) {
  const int tid  = threadIdx.x;
  const int lane = tid & 63;
  const int wid  = tid >> 6;
  const int g    = lane >> 4;   // 16-lane group within wave (0..3)
  const int e    = lane & 15;   // expert id owned by this lane
  const int rowbase = blockIdx.x * ROWS_PER_BLOCK + wid * (4 * R) + g * R;
  if (rowbase >= N) return;

  const float* __restrict__ wrow = W + e * D;           // this lane's expert row
  const float* __restrict__ xg   = x + (size_t)rowbase * D;

  float4 acc[R];
  #pragma unroll
  for (int r = 0; r < R; ++r) acc[r] = make_float4(0.f, 0.f, 0.f, 0.f);

  // Stream D in 32-float (128 B = one cache line) steps: W line cached in
  // registers (wv[8]) and reused across the group's R rows; each x line is
  // fully consumed by 8 back-to-back float4 loads (no L1 thrash window).
  for (int d0 = 0; d0 < D; d0 += 32) {
    float4 wv[8];
    #pragma unroll
    for (int j = 0; j < 8; ++j)
      wv[j] = *reinterpret_cast<const float4*>(wrow + d0 + 4 * j);
    #pragma unroll
    for (int r = 0; r < R; ++r) {
      const float* xr = xg + (size_t)r * D + d0;
      #pragma unroll
      for (int j = 0; j < 8; ++j) {
        const float4 xv = *reinterpret_cast<const float4*>(xr + 4 * j);
        acc[r].x = fmaf(xv.x, wv[j].x, acc[r].x);
        acc[r].y = fmaf(xv.y, wv[j].y, acc[r].y);
        acc[r].z = fmaf(xv.z, wv[j].z, acc[r].z);
        acc[r].w = fmaf(xv.w, wv[j].w, acc[r].w);
      }
    }
  }

  float s_i1 = 0.f, s_i2 = 0.f, s_g1 = 0.f, s_g2 = 0.f;

  #pragma unroll
  for (int r = 0; r < R; ++r) {
    // pairwise horizontal sum of the 4 accumulation chains
    float m1 = (acc[r].x + acc[r].y) + (acc[r].z + acc[r].w);
    int   i1 = e;
    float m2 = -FLT_MAX;
    int   i2 = E;
    // top-2 butterfly across the 16 expert lanes; lowest index wins ties
    // (matches jax.lax.top_k tie-breaking).
    #pragma unroll
    for (int mask = 1; mask < 16; mask <<= 1) {
      const float om1 = __shfl_xor(m1, mask);
      const int   oi1 = __shfl_xor(i1, mask);
      const float om2 = __shfl_xor(m2, mask);
      const int   oi2 = __shfl_xor(i2, mask);
      const bool bwin = (om1 > m1) || (om1 == m1 && oi1 < i1);
      const float a1 = bwin ? om1 : m1; const int ai1 = bwin ? oi1 : i1;
      const float l1 = bwin ? m1 : om1; const int li1 = bwin ? i1 : oi1;
      const float a2 = bwin ? om2 : m2; const int ai2 = bwin ? oi2 : i2;
      const bool lwin = (l1 > a2) || (l1 == a2 && li1 < ai2);
      m1 = a1; i1 = ai1;
      m2 = lwin ? l1 : a2; i2 = lwin ? li1 : ai2;
    }
    if (e == r) {   // lane r keeps row r's result for the coalesced store
      const float ex  = expf(m2 - m1);        // m2 <= m1, so ex in (0,1]
      const float inv = 1.0f / (1.0f + ex);
      s_i1 = (float)i1; s_i2 = (float)i2;
      s_g1 = inv;       s_g2 = ex * inv;
    }
  }

  if (e < R && rowbase + e < N) {
    const int row = rowbase + e;
    float2* outi = reinterpret_cast<float2*>(out);
    outi[row] = make_float2(s_i1, s_i2);
    float2* outw = reinterpret_cast<float2*>(out + (size_t)N * 2);
    outw[row] = make_float2(s_g1, s_g2);
  }
}

extern "C" void kernel_launch(void* const* d_in, const int* in_sizes, int n_in,
                              void* d_out, int out_size, void* d_ws, size_t ws_size,
                              hipStream_t stream) {
  const float* x = (const float*)d_in[0];
  const float* W = (const float*)d_in[1];
  float* out = (float*)d_out;
  const int N = in_sizes[0] / D;   // 131072
  const int grid = (N + ROWS_PER_BLOCK - 1) / ROWS_PER_BLOCK;  // 1024
  router_kernel<<<grid, BLOCK, 0, stream>>>(x, W, out, N);
}